// Round 4
// baseline (465.313 us; speedup 1.0000x reference)
//
#include <hip/hip_runtime.h>
#include <hip/hip_bf16.h>

#define N_NODES 20000
#define N_EDGES 2000
#define IN_FEATS 128
#define NUM_HEADS 4
#define OUT_FEATS 32
#define EDGE_DIM 64
#define C_FEATS 128   // NUM_HEADS*OUT_FEATS
#define NEG_SLOPE 0.2f
#define MAXD 256      // max pairs/edge bucket (mean 110, +14 sigma safe)
#define WT_LD 136     // padded LDS row (bf16 elems); 272B stride: b128 reads tile banks evenly
#define DCHUNK 1024
#define NBLK 512
#define NTHR 256
#define NTILES (N_NODES / 16)   // 1250 proj m-tiles

typedef __attribute__((ext_vector_type(8))) short bf16x8;
typedef __attribute__((ext_vector_type(4))) float f32x4;

__device__ __forceinline__ float leaky(float x) { return (x > 0.f) ? x : NEG_SLOPE * x; }
__device__ __forceinline__ short f2bf(float x) {
    __hip_bfloat16 h = __float2bfloat16(x);
    return *reinterpret_cast<short*>(&h);
}

// Resident-grid barrier: monotone counter, generation derived from own ticket.
// Requires all NBLK blocks co-resident (guaranteed: 2 blocks/CU at our LDS/VGPR).
// cnt is zeroed by hipMemsetAsync before each launch.
__device__ __forceinline__ void grid_sync(unsigned* cnt) {
    __syncthreads();
    if (threadIdx.x == 0) {
        __threadfence();   // release: make this block's writes device-visible
        unsigned t = __hip_atomic_fetch_add(cnt, 1u, __ATOMIC_RELEASE, __HIP_MEMORY_SCOPE_AGENT);
        unsigned goal = (t / NBLK + 1u) * NBLK;
        while (__hip_atomic_load(cnt, __ATOMIC_ACQUIRE, __HIP_MEMORY_SCOPE_AGENT) < goal)
            __builtin_amdgcn_s_sleep(2);
    }
    __syncthreads();
    __threadfence();       // acquire: invalidate L1 so all threads see other XCDs' writes
}

union SharedU {
    unsigned short Wt[128 * WT_LD];                 // proj phase: fc_w^T bf16  (34.8 KB)
    struct {
        float w_sh[MAXD][NUM_HEADS];
        int   n_sh[MAXD];
        float te_sh[NUM_HEADS];
        float inv_sh[NUM_HEADS];
        float wred[4][NUM_HEADS];
        float red[4][C_FEATS];
    } at;                                           // edge-attn phase (~7.3 KB)
    struct {
        int e_sh[DCHUNK];
        int ns_sh[33];
    } ds;                                           // disseminate phase (~4.2 KB)
};

__global__ __launch_bounds__(NTHR) void fused_kernel(
    const float* __restrict__ feat, const float* __restrict__ edge_feat,
    const float* __restrict__ fc_w, const float* __restrict__ attn_src,
    const float* __restrict__ attn_edge,
    const int* __restrict__ src_idx, const int* __restrict__ edge_idx, int P,
    float* __restrict__ s_buf, float* __restrict__ hef,
    __hip_bfloat16* __restrict__ feat_bf,
    int* __restrict__ cursor, int* __restrict__ node_start, int* __restrict__ edge_nodes,
    unsigned* __restrict__ barrier_cnt, float* __restrict__ out)
{
    __shared__ SharedU U;
    const int t = threadIdx.x;
    const int bid = blockIdx.x;
    const int gtid = bid * NTHR + t;

    // ================= Phase 1: zero cursors + MFMA projection =================
    if (gtid < N_EDGES) cursor[gtid] = 0;

    if (bid * 4 < NTILES) {
        // stage fc_w[k][c] -> Wt[c][k] bf16 (pairs of k for one 4B LDS store)
        for (int q = t; q < 64 * 128; q += NTHR) {
            const int c = q & 127, k = (q >> 7) * 2;
            U.Wt[c * WT_LD + k]     = (unsigned short)f2bf(fc_w[k * C_FEATS + c]);
            U.Wt[c * WT_LD + k + 1] = (unsigned short)f2bf(fc_w[(k + 1) * C_FEATS + c]);
        }
    }
    __syncthreads();

    {
        const int wave = t >> 6, lane = t & 63;
        const int wid = bid * 4 + wave;
        if (wid < NTILES) {
            const int m0 = wid * 16;
            const int lrow = lane & 15, lk = lane >> 4;

            bf16x8 afr[4];
            const float* arow = feat + (size_t)(m0 + lrow) * IN_FEATS + lk * 8;
            #pragma unroll
            for (int kt = 0; kt < 4; ++kt) {
                const float4 f0 = *(const float4*)(arow + kt * 32);
                const float4 f1 = *(const float4*)(arow + kt * 32 + 4);
                bf16x8 a;
                a[0] = f2bf(f0.x); a[1] = f2bf(f0.y); a[2] = f2bf(f0.z); a[3] = f2bf(f0.w);
                a[4] = f2bf(f1.x); a[5] = f2bf(f1.y); a[6] = f2bf(f1.z); a[7] = f2bf(f1.w);
                afr[kt] = a;
            }

            f32x4 acc[8];
            #pragma unroll
            for (int nt = 0; nt < 8; ++nt) acc[nt] = (f32x4){0.f, 0.f, 0.f, 0.f};
            #pragma unroll
            for (int nt = 0; nt < 8; ++nt) {
                const unsigned short* wrow = &U.Wt[(nt * 16 + lrow) * WT_LD + lk * 8];
                #pragma unroll
                for (int kt = 0; kt < 4; ++kt) {
                    const bf16x8 b = *(const bf16x8*)(wrow + kt * 32);
                    acc[nt] = __builtin_amdgcn_mfma_f32_16x16x32_bf16(afr[kt], b, acc[nt], 0, 0, 0);
                }
            }

            // C layout: col = lane&15, row = (lane>>4)*4 + reg
            #pragma unroll
            for (int nt = 0; nt < 8; ++nt) {
                const int c = nt * 16 + lrow;
                #pragma unroll
                for (int r = 0; r < 4; ++r)
                    feat_bf[(size_t)(m0 + lk * 4 + r) * C_FEATS + c] = __float2bfloat16(acc[nt][r]);
            }
            float aw[8];
            #pragma unroll
            for (int nt = 0; nt < 8; ++nt) aw[nt] = attn_src[nt * 16 + lrow];
            #pragma unroll
            for (int h = 0; h < NUM_HEADS; ++h) {
                #pragma unroll
                for (int r = 0; r < 4; ++r) {
                    float v = acc[2 * h][r] * aw[2 * h] + acc[2 * h + 1][r] * aw[2 * h + 1];
                    v += __shfl_xor(v, 1);
                    v += __shfl_xor(v, 2);
                    v += __shfl_xor(v, 4);
                    v += __shfl_xor(v, 8);
                    if (lrow == 0) s_buf[(m0 + lk * 4 + r) * NUM_HEADS + h] = v;
                }
            }
        }
    }

    grid_sync(barrier_cnt);

    // ================= Phase 2: bucket scatter + node_start ====================
    for (int p = gtid; p < P; p += NBLK * NTHR) {
        const int e = edge_idx[p];
        const int s = src_idx[p];
        const int pos = atomicAdd(&cursor[e], 1);
        if (pos < MAXD) edge_nodes[e * MAXD + pos] = s;
        const int prev = (p == 0) ? -1 : src_idx[p - 1];
        for (int n = prev + 1; n <= s; ++n) node_start[n] = p;
        if (p == P - 1)
            for (int n = s + 1; n <= N_NODES; ++n) node_start[n] = P;
    }

    grid_sync(barrier_cnt);

    // ================= Phase 3: per-edge softmax + aggregation =================
    for (int e = bid; e < N_EDGES; e += NBLK) {
        __syncthreads();   // guard LDS reuse across loop iterations
        const int wv = t >> 6, lane = t & 63;

        if (t < EDGE_DIM) {
            const float v = edge_feat[e * EDGE_DIM + t];
            #pragma unroll
            for (int h = 0; h < NUM_HEADS; ++h) {
                float p = v * attn_edge[h * EDGE_DIM + t];
                p += __shfl_xor(p, 32); p += __shfl_xor(p, 16); p += __shfl_xor(p, 8);
                p += __shfl_xor(p, 4);  p += __shfl_xor(p, 2);  p += __shfl_xor(p, 1);
                if (t == 0) U.at.te_sh[h] = p;
            }
        }
        __syncthreads();

        const int m = min(cursor[e], MAXD);

        float ps0 = 0.f, ps1 = 0.f, ps2 = 0.f, ps3 = 0.f;
        if (t < m) {
            const int n = edge_nodes[e * MAXD + t];
            U.at.n_sh[t] = n;
            const float4 s4 = *(const float4*)&s_buf[n * NUM_HEADS];
            const float w0 = __expf(leaky(s4.x + U.at.te_sh[0]));
            const float w1 = __expf(leaky(s4.y + U.at.te_sh[1]));
            const float w2 = __expf(leaky(s4.z + U.at.te_sh[2]));
            const float w3 = __expf(leaky(s4.w + U.at.te_sh[3]));
            U.at.w_sh[t][0] = w0; U.at.w_sh[t][1] = w1;
            U.at.w_sh[t][2] = w2; U.at.w_sh[t][3] = w3;
            ps0 = w0; ps1 = w1; ps2 = w2; ps3 = w3;
        }
        #pragma unroll
        for (int d = 32; d >= 1; d >>= 1) {
            ps0 += __shfl_xor(ps0, d); ps1 += __shfl_xor(ps1, d);
            ps2 += __shfl_xor(ps2, d); ps3 += __shfl_xor(ps3, d);
        }
        if (lane == 0) {
            U.at.wred[wv][0] = ps0; U.at.wred[wv][1] = ps1;
            U.at.wred[wv][2] = ps2; U.at.wred[wv][3] = ps3;
        }
        __syncthreads();
        if (t < NUM_HEADS)
            U.at.inv_sh[t] = 1.f / (U.at.wred[0][t] + U.at.wred[1][t] +
                                    U.at.wred[2][t] + U.at.wred[3][t] + 1e-9f);
        __syncthreads();

        const int c0 = lane * 2;
        const int h = lane >> 4;
        float a0 = 0.f, a1 = 0.f;
        const unsigned short* fb = (const unsigned short*)feat_bf;
        for (int j = wv; j < m; j += 4) {
            const int n = U.at.n_sh[j];
            const float w = U.at.w_sh[j][h];
            const unsigned v = *(const unsigned*)(fb + (size_t)n * C_FEATS + c0);
            a0 += w * __uint_as_float(v << 16);
            a1 += w * __uint_as_float(v & 0xffff0000u);
        }
        U.at.red[wv][c0] = a0;
        U.at.red[wv][c0 + 1] = a1;
        __syncthreads();
        if (t < C_FEATS) {
            const float r = U.at.red[0][t] + U.at.red[1][t] + U.at.red[2][t] + U.at.red[3][t];
            hef[e * C_FEATS + t] = r * U.at.inv_sh[t >> 5];
        }
    }

    grid_sync(barrier_cnt);

    // ================= Phase 4: disseminate (32 nodes / block-iter) ============
    for (int g = bid; g < N_NODES / 32; g += NBLK) {
        __syncthreads();
        const int n0 = g * 32;
        const int c = t & 127;
        const int base = (t >> 7) * 16;   // node half this thread serves
        if (t < 33) U.ds.ns_sh[t] = node_start[n0 + t];
        __syncthreads();
        const int s0 = U.ds.ns_sh[0], s1 = U.ds.ns_sh[32];

        float acc[16];
        #pragma unroll
        for (int r = 0; r < 16; ++r) acc[r] = 0.f;

        for (int cb = s0; cb < s1; cb += DCHUNK) {
            const int ccnt = min(DCHUNK, s1 - cb);
            __syncthreads();
            for (int i = t; i < ccnt; i += NTHR) U.ds.e_sh[i] = edge_idx[cb + i];
            __syncthreads();
            #pragma unroll 1
            for (int r = 0; r < 16; ++r) {
                const int jlo = max(U.ds.ns_sh[base + r], cb);
                const int jhi = min(U.ds.ns_sh[base + r + 1], cb + ccnt);
                float a = acc[r];
                for (int j = jlo; j < jhi; ++j)
                    a += hef[(size_t)U.ds.e_sh[j - cb] * C_FEATS + c];
                acc[r] = a;
            }
        }
        #pragma unroll
        for (int r = 0; r < 16; ++r)
            out[(size_t)(n0 + base + r) * C_FEATS + c] = acc[r];
    }
}

extern "C" void kernel_launch(void* const* d_in, const int* in_sizes, int n_in,
                              void* d_out, int out_size, void* d_ws, size_t ws_size,
                              hipStream_t stream) {
    const float* feat      = (const float*)d_in[0];
    const float* edge_feat = (const float*)d_in[1];
    // d_in[2] = H (dense incidence) — intentionally unused
    const float* fc_w      = (const float*)d_in[3];
    const float* attn_src  = (const float*)d_in[4];
    const float* attn_edge = (const float*)d_in[5];
    const int*   src_idx   = (const int*)d_in[6];
    const int*   edge_idx  = (const int*)d_in[7];
    const int P = in_sizes[6];
    float* out = (float*)d_out;

    float* ws = (float*)d_ws;
    float*          s_buf      = ws;                                          // 20000*4 f32
    float*          hef        = s_buf + N_NODES * NUM_HEADS;                 // 2000*128 f32
    __hip_bfloat16* feat_bf    = (__hip_bfloat16*)(hef + N_EDGES * C_FEATS);  // 20000*128 bf16
    int*            cursor     = (int*)(feat_bf + (size_t)N_NODES * C_FEATS); // 2000
    int*            node_start = cursor + N_EDGES;                            // 20001
    int*            edge_nodes = node_start + (N_NODES + 1);                  // 2000*MAXD
    unsigned*       bar        = (unsigned*)(edge_nodes + N_EDGES * MAXD);    // 1

    hipMemsetAsync(bar, 0, sizeof(unsigned), stream);
    fused_kernel<<<NBLK, NTHR, 0, stream>>>(
        feat, edge_feat, fc_w, attn_src, attn_edge, src_idx, edge_idx, P,
        s_buf, hef, feat_bf, cursor, node_start, edge_nodes, bar, out);
}

// Round 5
// 371.384 us; speedup vs baseline: 1.2529x; 1.2529x over previous
//
#include <hip/hip_runtime.h>
#include <hip/hip_bf16.h>

#define N_NODES 20000
#define N_EDGES 2000
#define IN_FEATS 128
#define NUM_HEADS 4
#define OUT_FEATS 32
#define EDGE_DIM 64
#define C_FEATS 128   // NUM_HEADS*OUT_FEATS
#define NEG_SLOPE 0.2f
#define MAXD 256      // max pairs/edge bucket (mean 110, +14 sigma safe)
#define WT_LD 136     // padded LDS row (bf16 elems)
#define DCHUNK 1024
#define NBLK 512
#define NTHR 256
#define NTILES (N_NODES / 16)   // 1250 proj m-tiles

typedef __attribute__((ext_vector_type(8))) short bf16x8;
typedef __attribute__((ext_vector_type(4))) float f32x4;

__device__ __forceinline__ float leaky(float x) { return (x > 0.f) ? x : NEG_SLOPE * x; }
__device__ __forceinline__ short f2bf(float x) {
    __hip_bfloat16 h = __float2bfloat16(x);
    return *reinterpret_cast<short*>(&h);
}

// Resident-grid barrier v2. R4 post-mortem: ACQUIRE-per-poll emitted cache
// maintenance every spin iteration -> chip-wide cache thrash (475us idle).
// Fix: RELAXED spin (scope-bit load, no invalidate), fences ONCE per barrier.
// cnt zeroed by hipMemsetAsync each call; monotone generations -> replay-safe.
__device__ __forceinline__ void grid_sync(unsigned* cnt) {
    __builtin_amdgcn_fence(__ATOMIC_RELEASE, "agent");   // flush once (all threads)
    __syncthreads();
    if (threadIdx.x == 0) {
        unsigned t = __hip_atomic_fetch_add(cnt, 1u, __ATOMIC_RELAXED, __HIP_MEMORY_SCOPE_AGENT);
        unsigned goal = (t / NBLK + 1u) * NBLK;
        while (__hip_atomic_load(cnt, __ATOMIC_RELAXED, __HIP_MEMORY_SCOPE_AGENT) < goal)
            __builtin_amdgcn_s_sleep(16);                // ~1k cycles between polls
    }
    __syncthreads();
    __builtin_amdgcn_fence(__ATOMIC_ACQUIRE, "agent");   // invalidate once (all threads)
}

union SharedU {
    unsigned short Wt[128 * WT_LD];                 // phase A: fc_w^T bf16 (34.8 KB)
    struct {
        float w_sh[MAXD][NUM_HEADS];
        int   n_sh[MAXD];
        float te_sh[NUM_HEADS];
        float inv_sh[NUM_HEADS];
        float wred[4][NUM_HEADS];
        float red[4][C_FEATS];
    } at;                                           // phase B (~7.3 KB)
    struct {
        int e_sh[DCHUNK];
        int ns_sh[33];
    } ds;                                           // phase C (~4.2 KB)
};

__global__ __launch_bounds__(NTHR) void fused_kernel(
    const float* __restrict__ feat, const float* __restrict__ edge_feat,
    const float* __restrict__ fc_w, const float* __restrict__ attn_src,
    const float* __restrict__ attn_edge,
    const int* __restrict__ src_idx, const int* __restrict__ edge_idx, int P,
    float* __restrict__ s_buf, float* __restrict__ hef,
    __hip_bfloat16* __restrict__ feat_bf,
    int* __restrict__ cursor, int* __restrict__ node_start, int* __restrict__ edge_nodes,
    unsigned* __restrict__ barrier_cnt, float* __restrict__ out)
{
    __shared__ SharedU U;
    const int t = threadIdx.x;
    const int bid = blockIdx.x;
    const int gtid = bid * NTHR + t;

    // ========== Phase A: MFMA projection (blocks 0..312) ∥ scatter (all blocks) ==========
    // (independent workloads; cursor pre-zeroed by the memset node)
    if (bid * 4 < NTILES) {
        for (int q = t; q < 64 * 128; q += NTHR) {
            const int c = q & 127, k = (q >> 7) * 2;
            U.Wt[c * WT_LD + k]     = (unsigned short)f2bf(fc_w[k * C_FEATS + c]);
            U.Wt[c * WT_LD + k + 1] = (unsigned short)f2bf(fc_w[(k + 1) * C_FEATS + c]);
        }
    }
    __syncthreads();

    {
        const int wave = t >> 6, lane = t & 63;
        const int wid = bid * 4 + wave;
        if (wid < NTILES) {
            const int m0 = wid * 16;
            const int lrow = lane & 15, lk = lane >> 4;

            bf16x8 afr[4];
            const float* arow = feat + (size_t)(m0 + lrow) * IN_FEATS + lk * 8;
            #pragma unroll
            for (int kt = 0; kt < 4; ++kt) {
                const float4 f0 = *(const float4*)(arow + kt * 32);
                const float4 f1 = *(const float4*)(arow + kt * 32 + 4);
                bf16x8 a;
                a[0] = f2bf(f0.x); a[1] = f2bf(f0.y); a[2] = f2bf(f0.z); a[3] = f2bf(f0.w);
                a[4] = f2bf(f1.x); a[5] = f2bf(f1.y); a[6] = f2bf(f1.z); a[7] = f2bf(f1.w);
                afr[kt] = a;
            }

            f32x4 acc[8];
            #pragma unroll
            for (int nt = 0; nt < 8; ++nt) acc[nt] = (f32x4){0.f, 0.f, 0.f, 0.f};
            #pragma unroll
            for (int nt = 0; nt < 8; ++nt) {
                const unsigned short* wrow = &U.Wt[(nt * 16 + lrow) * WT_LD + lk * 8];
                #pragma unroll
                for (int kt = 0; kt < 4; ++kt) {
                    const bf16x8 b = *(const bf16x8*)(wrow + kt * 32);
                    acc[nt] = __builtin_amdgcn_mfma_f32_16x16x32_bf16(afr[kt], b, acc[nt], 0, 0, 0);
                }
            }

            // C layout: col = lane&15, row = (lane>>4)*4 + reg
            #pragma unroll
            for (int nt = 0; nt < 8; ++nt) {
                const int c = nt * 16 + lrow;
                #pragma unroll
                for (int r = 0; r < 4; ++r)
                    feat_bf[(size_t)(m0 + lk * 4 + r) * C_FEATS + c] = __float2bfloat16(acc[nt][r]);
            }
            float aw[8];
            #pragma unroll
            for (int nt = 0; nt < 8; ++nt) aw[nt] = attn_src[nt * 16 + lrow];
            #pragma unroll
            for (int h = 0; h < NUM_HEADS; ++h) {
                #pragma unroll
                for (int r = 0; r < 4; ++r) {
                    float v = acc[2 * h][r] * aw[2 * h] + acc[2 * h + 1][r] * aw[2 * h + 1];
                    v += __shfl_xor(v, 1);
                    v += __shfl_xor(v, 2);
                    v += __shfl_xor(v, 4);
                    v += __shfl_xor(v, 8);
                    if (lrow == 0) s_buf[(m0 + lk * 4 + r) * NUM_HEADS + h] = v;
                }
            }
        }
    }

    // scatter + node_start (grid-strided over all blocks; independent of proj)
    for (int p = gtid; p < P; p += NBLK * NTHR) {
        const int e = edge_idx[p];
        const int s = src_idx[p];
        const int pos = atomicAdd(&cursor[e], 1);
        if (pos < MAXD) edge_nodes[e * MAXD + pos] = s;
        const int prev = (p == 0) ? -1 : src_idx[p - 1];
        for (int n = prev + 1; n <= s; ++n) node_start[n] = p;
        if (p == P - 1)
            for (int n = s + 1; n <= N_NODES; ++n) node_start[n] = P;
    }

    grid_sync(barrier_cnt);

    // ========== Phase B: per-edge softmax + aggregation ==========
    for (int e = bid; e < N_EDGES; e += NBLK) {
        __syncthreads();
        const int wv = t >> 6, lane = t & 63;

        if (t < EDGE_DIM) {
            const float v = edge_feat[e * EDGE_DIM + t];
            #pragma unroll
            for (int h = 0; h < NUM_HEADS; ++h) {
                float p = v * attn_edge[h * EDGE_DIM + t];
                p += __shfl_xor(p, 32); p += __shfl_xor(p, 16); p += __shfl_xor(p, 8);
                p += __shfl_xor(p, 4);  p += __shfl_xor(p, 2);  p += __shfl_xor(p, 1);
                if (t == 0) U.at.te_sh[h] = p;
            }
        }
        __syncthreads();

        const int m = min(cursor[e], MAXD);

        float ps0 = 0.f, ps1 = 0.f, ps2 = 0.f, ps3 = 0.f;
        if (t < m) {
            const int n = edge_nodes[e * MAXD + t];
            U.at.n_sh[t] = n;
            const float4 s4 = *(const float4*)&s_buf[n * NUM_HEADS];
            const float w0 = __expf(leaky(s4.x + U.at.te_sh[0]));
            const float w1 = __expf(leaky(s4.y + U.at.te_sh[1]));
            const float w2 = __expf(leaky(s4.z + U.at.te_sh[2]));
            const float w3 = __expf(leaky(s4.w + U.at.te_sh[3]));
            U.at.w_sh[t][0] = w0; U.at.w_sh[t][1] = w1;
            U.at.w_sh[t][2] = w2; U.at.w_sh[t][3] = w3;
            ps0 = w0; ps1 = w1; ps2 = w2; ps3 = w3;
        }
        #pragma unroll
        for (int d = 32; d >= 1; d >>= 1) {
            ps0 += __shfl_xor(ps0, d); ps1 += __shfl_xor(ps1, d);
            ps2 += __shfl_xor(ps2, d); ps3 += __shfl_xor(ps3, d);
        }
        if (lane == 0) {
            U.at.wred[wv][0] = ps0; U.at.wred[wv][1] = ps1;
            U.at.wred[wv][2] = ps2; U.at.wred[wv][3] = ps3;
        }
        __syncthreads();
        if (t < NUM_HEADS)
            U.at.inv_sh[t] = 1.f / (U.at.wred[0][t] + U.at.wred[1][t] +
                                    U.at.wred[2][t] + U.at.wred[3][t] + 1e-9f);
        __syncthreads();

        const int c0 = lane * 2;
        const int h = lane >> 4;
        float a0 = 0.f, a1 = 0.f;
        const unsigned short* fb = (const unsigned short*)feat_bf;
        for (int j = wv; j < m; j += 4) {
            const int n = U.at.n_sh[j];
            const float w = U.at.w_sh[j][h];
            const unsigned v = *(const unsigned*)(fb + (size_t)n * C_FEATS + c0);
            a0 += w * __uint_as_float(v << 16);
            a1 += w * __uint_as_float(v & 0xffff0000u);
        }
        U.at.red[wv][c0] = a0;
        U.at.red[wv][c0 + 1] = a1;
        __syncthreads();
        if (t < C_FEATS) {
            const float r = U.at.red[0][t] + U.at.red[1][t] + U.at.red[2][t] + U.at.red[3][t];
            hef[e * C_FEATS + t] = r * U.at.inv_sh[t >> 5];
        }
    }

    grid_sync(barrier_cnt);

    // ========== Phase C: disseminate (32 nodes / block-iter) ==========
    for (int g = bid; g < N_NODES / 32; g += NBLK) {
        __syncthreads();
        const int n0 = g * 32;
        const int c = t & 127;
        const int base = (t >> 7) * 16;
        if (t < 33) U.ds.ns_sh[t] = node_start[n0 + t];
        __syncthreads();
        const int s0 = U.ds.ns_sh[0], s1 = U.ds.ns_sh[32];

        float acc[16];
        #pragma unroll
        for (int r = 0; r < 16; ++r) acc[r] = 0.f;

        for (int cb = s0; cb < s1; cb += DCHUNK) {
            const int ccnt = min(DCHUNK, s1 - cb);
            __syncthreads();
            for (int i = t; i < ccnt; i += NTHR) U.ds.e_sh[i] = edge_idx[cb + i];
            __syncthreads();
            #pragma unroll 1
            for (int r = 0; r < 16; ++r) {
                const int jlo = max(U.ds.ns_sh[base + r], cb);
                const int jhi = min(U.ds.ns_sh[base + r + 1], cb + ccnt);
                float a = acc[r];
                for (int j = jlo; j < jhi; ++j)
                    a += hef[(size_t)U.ds.e_sh[j - cb] * C_FEATS + c];
                acc[r] = a;
            }
        }
        #pragma unroll
        for (int r = 0; r < 16; ++r)
            out[(size_t)(n0 + base + r) * C_FEATS + c] = acc[r];
    }
}

extern "C" void kernel_launch(void* const* d_in, const int* in_sizes, int n_in,
                              void* d_out, int out_size, void* d_ws, size_t ws_size,
                              hipStream_t stream) {
    const float* feat      = (const float*)d_in[0];
    const float* edge_feat = (const float*)d_in[1];
    // d_in[2] = H (dense incidence) — intentionally unused
    const float* fc_w      = (const float*)d_in[3];
    const float* attn_src  = (const float*)d_in[4];
    const float* attn_edge = (const float*)d_in[5];
    const int*   src_idx   = (const int*)d_in[6];
    const int*   edge_idx  = (const int*)d_in[7];
    const int P = in_sizes[6];
    float* out = (float*)d_out;

    float* ws = (float*)d_ws;
    float*          s_buf      = ws;                                          // 20000*4 f32
    float*          hef        = s_buf + N_NODES * NUM_HEADS;                 // 2000*128 f32
    __hip_bfloat16* feat_bf    = (__hip_bfloat16*)(hef + N_EDGES * C_FEATS);  // 20000*128 bf16
    int*            node_start = (int*)(feat_bf + (size_t)N_NODES * C_FEATS); // 20001
    int*            edge_nodes = node_start + (N_NODES + 1);                  // 2000*MAXD
    unsigned*       bar        = (unsigned*)(edge_nodes + N_EDGES * MAXD);    // 1
    int*            cursor     = (int*)(bar + 1);                             // 2000 (contiguous w/ bar)

    // one memset node zeroes barrier counter + cursors
    hipMemsetAsync(bar, 0, sizeof(unsigned) + N_EDGES * sizeof(int), stream);
    fused_kernel<<<NBLK, NTHR, 0, stream>>>(
        feat, edge_feat, fc_w, attn_src, attn_edge, src_idx, edge_idx, P,
        s_buf, hef, feat_bf, cursor, node_start, edge_nodes, bar, out);
}

// Round 6
// 74.378 us; speedup vs baseline: 6.2560x; 4.9932x over previous
//
#include <hip/hip_runtime.h>
#include <hip/hip_bf16.h>

#define N_NODES 20000
#define N_EDGES 2000
#define IN_FEATS 128
#define NUM_HEADS 4
#define OUT_FEATS 32
#define EDGE_DIM 64
#define C_FEATS 128   // NUM_HEADS*OUT_FEATS
#define NEG_SLOPE 0.2f
#define MAXD 256      // max pairs/edge bucket (mean 110, max~150, +14 sigma safe)
#define WT_LD 136     // padded LDS row (bf16 elems)
#define NTILES (N_NODES / 16)   // 1250 proj m-tiles
#define K1_BLK 512
#define K1_THR 256

typedef __attribute__((ext_vector_type(8))) short bf16x8;
typedef __attribute__((ext_vector_type(4))) float f32x4;

__device__ __forceinline__ float leaky(float x) { return (x > 0.f) ? x : NEG_SLOPE * x; }
__device__ __forceinline__ short f2bf(float x) {
    __hip_bfloat16 h = __float2bfloat16(x);
    return *reinterpret_cast<short*>(&h);
}

// ---------------------------------------------------------------------------
// K1: MFMA projection (waves 0..1249 across blocks 0..312) AND grid-strided
// bucket scatter + node_start build (all 512 blocks). The two workloads are
// data-independent -> merged into one dispatch with no internal sync.
// Cross-kernel visibility is provided by the dispatch boundary (cheap, CP-done)
// -- R4/R5 showed in-kernel cross-XCD fences cost ~175us/barrier. Avoided.
// ---------------------------------------------------------------------------
__global__ __launch_bounds__(K1_THR) void proj_scatter_kernel(
    const float* __restrict__ feat, const float* __restrict__ fc_w,
    const float* __restrict__ attn_src,
    const int* __restrict__ src_idx, const int* __restrict__ edge_idx, int P,
    __hip_bfloat16* __restrict__ feat_bf, float* __restrict__ s_buf,
    int* __restrict__ cursor, int* __restrict__ node_start, int* __restrict__ edge_nodes)
{
    __shared__ unsigned short Wt[128 * WT_LD];
    const int t = threadIdx.x;
    const int bid = blockIdx.x;

    // ---- projection part (blocks 0..312 only) ----
    if (bid * 4 < NTILES) {
        for (int q = t; q < 64 * 128; q += K1_THR) {
            const int c = q & 127, k = (q >> 7) * 2;
            Wt[c * WT_LD + k]     = (unsigned short)f2bf(fc_w[k * C_FEATS + c]);
            Wt[c * WT_LD + k + 1] = (unsigned short)f2bf(fc_w[(k + 1) * C_FEATS + c]);
        }
        __syncthreads();

        const int wave = t >> 6, lane = t & 63;
        const int wid = bid * 4 + wave;
        if (wid < NTILES) {
            const int m0 = wid * 16;
            const int lrow = lane & 15, lk = lane >> 4;

            bf16x8 afr[4];
            const float* arow = feat + (size_t)(m0 + lrow) * IN_FEATS + lk * 8;
            #pragma unroll
            for (int kt = 0; kt < 4; ++kt) {
                const float4 f0 = *(const float4*)(arow + kt * 32);
                const float4 f1 = *(const float4*)(arow + kt * 32 + 4);
                bf16x8 a;
                a[0] = f2bf(f0.x); a[1] = f2bf(f0.y); a[2] = f2bf(f0.z); a[3] = f2bf(f0.w);
                a[4] = f2bf(f1.x); a[5] = f2bf(f1.y); a[6] = f2bf(f1.z); a[7] = f2bf(f1.w);
                afr[kt] = a;
            }

            f32x4 acc[8];
            #pragma unroll
            for (int nt = 0; nt < 8; ++nt) acc[nt] = (f32x4){0.f, 0.f, 0.f, 0.f};
            #pragma unroll
            for (int nt = 0; nt < 8; ++nt) {
                const unsigned short* wrow = &Wt[(nt * 16 + lrow) * WT_LD + lk * 8];
                #pragma unroll
                for (int kt = 0; kt < 4; ++kt) {
                    const bf16x8 b = *(const bf16x8*)(wrow + kt * 32);
                    acc[nt] = __builtin_amdgcn_mfma_f32_16x16x32_bf16(afr[kt], b, acc[nt], 0, 0, 0);
                }
            }

            // C layout: col = lane&15, row = (lane>>4)*4 + reg  (m89-verified)
            #pragma unroll
            for (int nt = 0; nt < 8; ++nt) {
                const int c = nt * 16 + lrow;
                #pragma unroll
                for (int r = 0; r < 4; ++r)
                    feat_bf[(size_t)(m0 + lk * 4 + r) * C_FEATS + c] = __float2bfloat16(acc[nt][r]);
            }
            float aw[8];
            #pragma unroll
            for (int nt = 0; nt < 8; ++nt) aw[nt] = attn_src[nt * 16 + lrow];
            #pragma unroll
            for (int h = 0; h < NUM_HEADS; ++h) {
                #pragma unroll
                for (int r = 0; r < 4; ++r) {
                    float v = acc[2 * h][r] * aw[2 * h] + acc[2 * h + 1][r] * aw[2 * h + 1];
                    v += __shfl_xor(v, 1);
                    v += __shfl_xor(v, 2);
                    v += __shfl_xor(v, 4);
                    v += __shfl_xor(v, 8);
                    if (lrow == 0) s_buf[(m0 + lk * 4 + r) * NUM_HEADS + h] = v;
                }
            }
        }
    }

    // ---- scatter part (all blocks, grid-strided) ----
    for (int p = bid * K1_THR + t; p < P; p += K1_BLK * K1_THR) {
        const int e = edge_idx[p];
        const int s = src_idx[p];
        const int pos = atomicAdd(&cursor[e], 1);
        if (pos < MAXD) edge_nodes[e * MAXD + pos] = s;
        const int prev = (p == 0) ? -1 : src_idx[p - 1];
        for (int n = prev + 1; n <= s; ++n) node_start[n] = p;
        if (p == P - 1)
            for (int n = s + 1; n <= N_NODES; ++n) node_start[n] = P;
    }
}

// ---------------------------------------------------------------------------
// K2: per-edge softmax + aggregation. Block = 1 edge, 256 threads.
// Max-free softmax (scores bounded; exp cannot overflow f32 here).
// ---------------------------------------------------------------------------
__global__ __launch_bounds__(256) void edge_attn_kernel(
    const float* __restrict__ s_buf, const float* __restrict__ edge_feat,
    const float* __restrict__ attn_edge, const __hip_bfloat16* __restrict__ feat_bf,
    const int* __restrict__ cursor, const int* __restrict__ edge_nodes,
    float* __restrict__ hef)
{
    __shared__ float4 w_sh[MAXD];
    __shared__ int    n_sh[MAXD];
    __shared__ float  te_sh[NUM_HEADS];
    __shared__ float  inv_sh[NUM_HEADS];
    __shared__ float  wred[4][NUM_HEADS];
    __shared__ float  red[4][C_FEATS];

    const int e = blockIdx.x;
    const int t = threadIdx.x;
    const int wv = t >> 6, lane = t & 63;

    // fused edge projection te[h] = <edge_feat[e,:], attn_edge[h,:]>
    if (t < EDGE_DIM) {
        const float v = edge_feat[e * EDGE_DIM + t];
        #pragma unroll
        for (int h = 0; h < NUM_HEADS; ++h) {
            float p = v * attn_edge[h * EDGE_DIM + t];
            p += __shfl_xor(p, 32); p += __shfl_xor(p, 16); p += __shfl_xor(p, 8);
            p += __shfl_xor(p, 4);  p += __shfl_xor(p, 2);  p += __shfl_xor(p, 1);
            if (t == 0) te_sh[h] = p;
        }
    }
    __syncthreads();

    const int m = min(cursor[e], MAXD);

    float ps0 = 0.f, ps1 = 0.f, ps2 = 0.f, ps3 = 0.f;
    if (t < m) {
        const int n = edge_nodes[e * MAXD + t];
        n_sh[t] = n;
        const float4 s4 = *(const float4*)&s_buf[n * NUM_HEADS];
        float4 w;
        w.x = __expf(leaky(s4.x + te_sh[0]));
        w.y = __expf(leaky(s4.y + te_sh[1]));
        w.z = __expf(leaky(s4.z + te_sh[2]));
        w.w = __expf(leaky(s4.w + te_sh[3]));
        w_sh[t] = w;
        ps0 = w.x; ps1 = w.y; ps2 = w.z; ps3 = w.w;
    }
    #pragma unroll
    for (int d = 32; d >= 1; d >>= 1) {
        ps0 += __shfl_xor(ps0, d); ps1 += __shfl_xor(ps1, d);
        ps2 += __shfl_xor(ps2, d); ps3 += __shfl_xor(ps3, d);
    }
    if (lane == 0) {
        wred[wv][0] = ps0; wred[wv][1] = ps1; wred[wv][2] = ps2; wred[wv][3] = ps3;
    }
    __syncthreads();
    if (t < NUM_HEADS)
        inv_sh[t] = 1.f / (wred[0][t] + wred[1][t] + wred[2][t] + wred[3][t] + 1e-9f);
    __syncthreads();

    // aggregation: substream wv handles pairs j = wv, wv+4, ...; unroll-4 keeps
    // 4 independent gather loads in flight (break the LDS->global latency chain)
    const int c0 = lane * 2;
    const int h = lane >> 4;
    float a0 = 0.f, a1 = 0.f;
    const unsigned short* fb = (const unsigned short*)feat_bf;
    #pragma unroll 4
    for (int j = wv; j < m; j += 4) {
        const int n = n_sh[j];
        const float w = ((const float*)&w_sh[j])[h];
        const unsigned v = *(const unsigned*)(fb + (size_t)n * C_FEATS + c0);
        a0 += w * __uint_as_float(v << 16);
        a1 += w * __uint_as_float(v & 0xffff0000u);
    }
    red[wv][c0] = a0;
    red[wv][c0 + 1] = a1;
    __syncthreads();
    if (t < C_FEATS) {
        const float r = red[0][t] + red[1][t] + red[2][t] + red[3][t];
        hef[e * C_FEATS + t] = r * inv_sh[t >> 5];
    }
}

// ---------------------------------------------------------------------------
// K3: disseminate. Block = 8 nodes, 128 threads (one channel each). Block's
// pair range is contiguous (src_idx sorted) -> stage edge ids coalesced in LDS,
// then per-node accumulate over hef rows (1MB, L2-resident). unroll-4 for MLP.
// ---------------------------------------------------------------------------
#define K3_NODES 8
#define K3_CHUNK 512
__global__ __launch_bounds__(128) void disseminate_kernel(
    const int* __restrict__ node_start, const int* __restrict__ edge_idx,
    const float* __restrict__ hef, float* __restrict__ out)
{
    __shared__ int e_sh[K3_CHUNK];
    __shared__ int ns_sh[K3_NODES + 1];
    const int n0 = blockIdx.x * K3_NODES;
    const int c = threadIdx.x;
    if (c < K3_NODES + 1) ns_sh[c] = node_start[n0 + c];
    __syncthreads();
    const int s0 = ns_sh[0], s1 = ns_sh[K3_NODES];

    float acc[K3_NODES];
    #pragma unroll
    for (int r = 0; r < K3_NODES; ++r) acc[r] = 0.f;

    for (int cb = s0; cb < s1; cb += K3_CHUNK) {
        const int ccnt = min(K3_CHUNK, s1 - cb);
        __syncthreads();
        for (int i = c; i < ccnt; i += 128) e_sh[i] = edge_idx[cb + i];
        __syncthreads();
        #pragma unroll 1
        for (int r = 0; r < K3_NODES; ++r) {
            const int jlo = max(ns_sh[r], cb);
            const int jhi = min(ns_sh[r + 1], cb + ccnt);
            float a = acc[r];
            #pragma unroll 4
            for (int j = jlo; j < jhi; ++j)
                a += hef[(size_t)e_sh[j - cb] * C_FEATS + c];
            acc[r] = a;
        }
    }
    #pragma unroll
    for (int r = 0; r < K3_NODES; ++r)
        out[(size_t)(n0 + r) * C_FEATS + c] = acc[r];
}

extern "C" void kernel_launch(void* const* d_in, const int* in_sizes, int n_in,
                              void* d_out, int out_size, void* d_ws, size_t ws_size,
                              hipStream_t stream) {
    const float* feat      = (const float*)d_in[0];
    const float* edge_feat = (const float*)d_in[1];
    // d_in[2] = H (dense incidence) — intentionally unused
    const float* fc_w      = (const float*)d_in[3];
    const float* attn_src  = (const float*)d_in[4];
    const float* attn_edge = (const float*)d_in[5];
    const int*   src_idx   = (const int*)d_in[6];
    const int*   edge_idx  = (const int*)d_in[7];
    const int P = in_sizes[6];
    float* out = (float*)d_out;

    float* ws = (float*)d_ws;
    float*          s_buf      = ws;                                          // 20000*4 f32
    float*          hef        = s_buf + N_NODES * NUM_HEADS;                 // 2000*128 f32
    __hip_bfloat16* feat_bf    = (__hip_bfloat16*)(hef + N_EDGES * C_FEATS);  // 20000*128 bf16
    int*            node_start = (int*)(feat_bf + (size_t)N_NODES * C_FEATS); // 20001
    int*            edge_nodes = node_start + (N_NODES + 1);                  // 2000*MAXD
    int*            cursor     = edge_nodes + N_EDGES * MAXD;                 // 2000

    hipMemsetAsync(cursor, 0, N_EDGES * sizeof(int), stream);
    proj_scatter_kernel<<<K1_BLK, K1_THR, 0, stream>>>(
        feat, fc_w, attn_src, src_idx, edge_idx, P,
        feat_bf, s_buf, cursor, node_start, edge_nodes);
    edge_attn_kernel<<<N_EDGES, 256, 0, stream>>>(
        s_buf, edge_feat, attn_edge, feat_bf, cursor, edge_nodes, hef);
    disseminate_kernel<<<N_NODES / K3_NODES, 128, 0, stream>>>(
        node_start, edge_idx, hef, out);
}

// Round 7
// 57.114 us; speedup vs baseline: 8.1471x; 1.3023x over previous
//
#include <hip/hip_runtime.h>
#include <hip/hip_bf16.h>

#define N_NODES 20000
#define N_EDGES 2000
#define IN_FEATS 128
#define NUM_HEADS 4
#define OUT_FEATS 32
#define EDGE_DIM 64
#define C_FEATS 128   // NUM_HEADS*OUT_FEATS
#define NEG_SLOPE 0.2f
#define MAXD 256      // max pairs/edge bucket (mean 110, max~160, +14 sigma safe)
#define WT_LD 136     // padded LDS row (bf16 elems)
#define NTILES (N_NODES / 16)        // 1250 proj m-tiles
#define PROJ_BLKS ((NTILES + 3) / 4) // 313 proj blocks (4 waves each)
#define K1_BLK 512
#define K1_THR 256
#define CUR_STRIDE 16 // cursor padded to 1 counter / 64B line (atomic-serialization fix)

typedef __attribute__((ext_vector_type(8))) short bf16x8;
typedef __attribute__((ext_vector_type(4))) float f32x4;

__device__ __forceinline__ float leaky(float x) { return (x > 0.f) ? x : NEG_SLOPE * x; }
__device__ __forceinline__ short f2bf(float x) {
    __hip_bfloat16 h = __float2bfloat16(x);
    return *reinterpret_cast<short*>(&h);
}

// ---------------------------------------------------------------------------
// K1: blocks 0..PROJ_BLKS-1: MFMA projection; blocks PROJ_BLKS..511: bucket
// scatter + node_start build. Role split keeps each block's critical path short.
// ---------------------------------------------------------------------------
__global__ __launch_bounds__(K1_THR) void proj_scatter_kernel(
    const float* __restrict__ feat, const float* __restrict__ fc_w,
    const float* __restrict__ attn_src,
    const int* __restrict__ src_idx, const int* __restrict__ edge_idx, int P,
    __hip_bfloat16* __restrict__ feat_bf, float* __restrict__ s_buf,
    int* __restrict__ cursor, int* __restrict__ node_start, int* __restrict__ edge_nodes)
{
    __shared__ unsigned short Wt[128 * WT_LD];
    const int t = threadIdx.x;
    const int bid = blockIdx.x;

    if (bid < PROJ_BLKS) {
        // ---- projection ----
        for (int q = t; q < 64 * 128; q += K1_THR) {
            const int c = q & 127, k = (q >> 7) * 2;
            Wt[c * WT_LD + k]     = (unsigned short)f2bf(fc_w[k * C_FEATS + c]);
            Wt[c * WT_LD + k + 1] = (unsigned short)f2bf(fc_w[(k + 1) * C_FEATS + c]);
        }
        __syncthreads();

        const int wave = t >> 6, lane = t & 63;
        const int wid = bid * 4 + wave;
        if (wid < NTILES) {
            const int m0 = wid * 16;
            const int lrow = lane & 15, lk = lane >> 4;

            bf16x8 afr[4];
            const float* arow = feat + (size_t)(m0 + lrow) * IN_FEATS + lk * 8;
            #pragma unroll
            for (int kt = 0; kt < 4; ++kt) {
                const float4 f0 = *(const float4*)(arow + kt * 32);
                const float4 f1 = *(const float4*)(arow + kt * 32 + 4);
                bf16x8 a;
                a[0] = f2bf(f0.x); a[1] = f2bf(f0.y); a[2] = f2bf(f0.z); a[3] = f2bf(f0.w);
                a[4] = f2bf(f1.x); a[5] = f2bf(f1.y); a[6] = f2bf(f1.z); a[7] = f2bf(f1.w);
                afr[kt] = a;
            }

            f32x4 acc[8];
            #pragma unroll
            for (int nt = 0; nt < 8; ++nt) acc[nt] = (f32x4){0.f, 0.f, 0.f, 0.f};
            #pragma unroll
            for (int nt = 0; nt < 8; ++nt) {
                const unsigned short* wrow = &Wt[(nt * 16 + lrow) * WT_LD + lk * 8];
                #pragma unroll
                for (int kt = 0; kt < 4; ++kt) {
                    const bf16x8 b = *(const bf16x8*)(wrow + kt * 32);
                    acc[nt] = __builtin_amdgcn_mfma_f32_16x16x32_bf16(afr[kt], b, acc[nt], 0, 0, 0);
                }
            }

            // C layout: col = lane&15, row = (lane>>4)*4 + reg  (m89-verified)
            #pragma unroll
            for (int nt = 0; nt < 8; ++nt) {
                const int c = nt * 16 + lrow;
                #pragma unroll
                for (int r = 0; r < 4; ++r)
                    feat_bf[(size_t)(m0 + lk * 4 + r) * C_FEATS + c] = __float2bfloat16(acc[nt][r]);
            }
            float aw[8];
            #pragma unroll
            for (int nt = 0; nt < 8; ++nt) aw[nt] = attn_src[nt * 16 + lrow];
            #pragma unroll
            for (int h = 0; h < NUM_HEADS; ++h) {
                #pragma unroll
                for (int r = 0; r < 4; ++r) {
                    float v = acc[2 * h][r] * aw[2 * h] + acc[2 * h + 1][r] * aw[2 * h + 1];
                    v += __shfl_xor(v, 1);
                    v += __shfl_xor(v, 2);
                    v += __shfl_xor(v, 4);
                    v += __shfl_xor(v, 8);
                    if (lrow == 0) s_buf[(m0 + lk * 4 + r) * NUM_HEADS + h] = v;
                }
            }
        }
    } else {
        // ---- scatter (blocks PROJ_BLKS..511, grid-strided) ----
        const int nthreads = (K1_BLK - PROJ_BLKS) * K1_THR;
        for (int p = (bid - PROJ_BLKS) * K1_THR + t; p < P; p += nthreads) {
            const int e = edge_idx[p];
            const int s = src_idx[p];
            const int pos = atomicAdd(&cursor[e * CUR_STRIDE], 1);
            if (pos < MAXD) edge_nodes[e * MAXD + pos] = s;
            const int prev = (p == 0) ? -1 : src_idx[p - 1];
            for (int n = prev + 1; n <= s; ++n) node_start[n] = p;
            if (p == P - 1)
                for (int n = s + 1; n <= N_NODES; ++n) node_start[n] = P;
        }
    }
}

// ---------------------------------------------------------------------------
// K2: per-edge softmax + aggregation. Block = 1 edge, 256 threads.
// Max-free softmax (scores bounded; exp cannot overflow f32).
// Weight/node staging padded to a multiple of 32 with w=0 entries so the
// aggregation loop is branch-free and cleanly unrolled (8 gathers in flight).
// ---------------------------------------------------------------------------
__global__ __launch_bounds__(256) void edge_attn_kernel(
    const float* __restrict__ s_buf, const float* __restrict__ edge_feat,
    const float* __restrict__ attn_edge, const __hip_bfloat16* __restrict__ feat_bf,
    const int* __restrict__ cursor, const int* __restrict__ edge_nodes,
    float* __restrict__ hef)
{
    __shared__ float4 w_sh[MAXD];
    __shared__ int    n_sh[MAXD];
    __shared__ float  te_sh[NUM_HEADS];
    __shared__ float  inv_sh[NUM_HEADS];
    __shared__ float  wred[4][NUM_HEADS];
    __shared__ float  red[4][C_FEATS];

    const int e = blockIdx.x;
    const int t = threadIdx.x;
    const int wv = t >> 6, lane = t & 63;

    // fused edge projection te[h] = <edge_feat[e,:], attn_edge[h,:]>
    if (t < EDGE_DIM) {
        const float v = edge_feat[e * EDGE_DIM + t];
        #pragma unroll
        for (int h = 0; h < NUM_HEADS; ++h) {
            float p = v * attn_edge[h * EDGE_DIM + t];
            p += __shfl_xor(p, 32); p += __shfl_xor(p, 16); p += __shfl_xor(p, 8);
            p += __shfl_xor(p, 4);  p += __shfl_xor(p, 2);  p += __shfl_xor(p, 1);
            if (t == 0) te_sh[h] = p;
        }
    }
    __syncthreads();

    const int m = min(cursor[e * CUR_STRIDE], MAXD);
    const int m_pad = (m + 31) & ~31;

    float ps0 = 0.f, ps1 = 0.f, ps2 = 0.f, ps3 = 0.f;
    if (t < m) {
        const int n = edge_nodes[e * MAXD + t];
        n_sh[t] = n;
        const float4 s4 = *(const float4*)&s_buf[n * NUM_HEADS];
        float4 w;
        w.x = __expf(leaky(s4.x + te_sh[0]));
        w.y = __expf(leaky(s4.y + te_sh[1]));
        w.z = __expf(leaky(s4.z + te_sh[2]));
        w.w = __expf(leaky(s4.w + te_sh[3]));
        w_sh[t] = w;
        ps0 = w.x; ps1 = w.y; ps2 = w.z; ps3 = w.w;
    } else if (t < m_pad) {
        n_sh[t] = 0;
        w_sh[t] = make_float4(0.f, 0.f, 0.f, 0.f);   // exact no-op in all sums
    }
    #pragma unroll
    for (int d = 32; d >= 1; d >>= 1) {
        ps0 += __shfl_xor(ps0, d); ps1 += __shfl_xor(ps1, d);
        ps2 += __shfl_xor(ps2, d); ps3 += __shfl_xor(ps3, d);
    }
    if (lane == 0) {
        wred[wv][0] = ps0; wred[wv][1] = ps1; wred[wv][2] = ps2; wred[wv][3] = ps3;
    }
    __syncthreads();
    if (t < NUM_HEADS)
        inv_sh[t] = 1.f / (wred[0][t] + wred[1][t] + wred[2][t] + wred[3][t] + 1e-9f);
    __syncthreads();

    // aggregation: substream wv handles j = wv, wv+4, ...; branch-free over m_pad
    const int c0 = lane * 2;
    const int h = lane >> 4;
    float a0 = 0.f, a1 = 0.f;
    const unsigned short* fb = (const unsigned short*)feat_bf;
    #pragma unroll 8
    for (int j = wv; j < m_pad; j += 4) {
        const int n = n_sh[j];
        const float w = ((const float*)&w_sh[j])[h];
        const unsigned v = *(const unsigned*)(fb + (size_t)n * C_FEATS + c0);
        a0 += w * __uint_as_float(v << 16);
        a1 += w * __uint_as_float(v & 0xffff0000u);
    }
    red[wv][c0] = a0;
    red[wv][c0 + 1] = a1;
    __syncthreads();
    if (t < C_FEATS) {
        const float r = red[0][t] + red[1][t] + red[2][t] + red[3][t];
        hef[e * C_FEATS + t] = r * inv_sh[t >> 5];
    }
}

// ---------------------------------------------------------------------------
// K3: disseminate. Block = 8 nodes, 128 threads (one channel each). Block's
// pair range is contiguous (src_idx sorted) -> stage edge ids coalesced in LDS,
// then per-node accumulate over hef rows (1MB, L2-resident). unroll-8 MLP.
// ---------------------------------------------------------------------------
#define K3_NODES 8
#define K3_CHUNK 512
__global__ __launch_bounds__(128) void disseminate_kernel(
    const int* __restrict__ node_start, const int* __restrict__ edge_idx,
    const float* __restrict__ hef, float* __restrict__ out)
{
    __shared__ int e_sh[K3_CHUNK];
    __shared__ int ns_sh[K3_NODES + 1];
    const int n0 = blockIdx.x * K3_NODES;
    const int c = threadIdx.x;
    if (c < K3_NODES + 1) ns_sh[c] = node_start[n0 + c];
    __syncthreads();
    const int s0 = ns_sh[0], s1 = ns_sh[K3_NODES];

    float acc[K3_NODES];
    #pragma unroll
    for (int r = 0; r < K3_NODES; ++r) acc[r] = 0.f;

    for (int cb = s0; cb < s1; cb += K3_CHUNK) {
        const int ccnt = min(K3_CHUNK, s1 - cb);
        __syncthreads();
        for (int i = c; i < ccnt; i += 128) e_sh[i] = edge_idx[cb + i];
        __syncthreads();
        #pragma unroll 1
        for (int r = 0; r < K3_NODES; ++r) {
            const int jlo = max(ns_sh[r], cb);
            const int jhi = min(ns_sh[r + 1], cb + ccnt);
            float a = acc[r];
            #pragma unroll 8
            for (int j = jlo; j < jhi; ++j)
                a += hef[(size_t)e_sh[j - cb] * C_FEATS + c];
            acc[r] = a;
        }
    }
    #pragma unroll
    for (int r = 0; r < K3_NODES; ++r)
        out[(size_t)(n0 + r) * C_FEATS + c] = acc[r];
}

extern "C" void kernel_launch(void* const* d_in, const int* in_sizes, int n_in,
                              void* d_out, int out_size, void* d_ws, size_t ws_size,
                              hipStream_t stream) {
    const float* feat      = (const float*)d_in[0];
    const float* edge_feat = (const float*)d_in[1];
    // d_in[2] = H (dense incidence) — intentionally unused
    const float* fc_w      = (const float*)d_in[3];
    const float* attn_src  = (const float*)d_in[4];
    const float* attn_edge = (const float*)d_in[5];
    const int*   src_idx   = (const int*)d_in[6];
    const int*   edge_idx  = (const int*)d_in[7];
    const int P = in_sizes[6];
    float* out = (float*)d_out;

    float* ws = (float*)d_ws;
    float*          s_buf      = ws;                                          // 20000*4 f32
    float*          hef        = s_buf + N_NODES * NUM_HEADS;                 // 2000*128 f32
    __hip_bfloat16* feat_bf    = (__hip_bfloat16*)(hef + N_EDGES * C_FEATS);  // 20000*128 bf16
    int*            node_start = (int*)(feat_bf + (size_t)N_NODES * C_FEATS); // 20001
    int*            edge_nodes = node_start + (N_NODES + 1);                  // 2000*MAXD
    int*            cursor     = edge_nodes + N_EDGES * MAXD;                 // 2000*CUR_STRIDE

    hipMemsetAsync(cursor, 0, N_EDGES * CUR_STRIDE * sizeof(int), stream);
    proj_scatter_kernel<<<K1_BLK, K1_THR, 0, stream>>>(
        feat, fc_w, attn_src, src_idx, edge_idx, P,
        feat_bf, s_buf, cursor, node_start, edge_nodes);
    edge_attn_kernel<<<N_EDGES, 256, 0, stream>>>(
        s_buf, edge_feat, attn_edge, feat_bf, cursor, edge_nodes, hef);
    disseminate_kernel<<<N_NODES / K3_NODES, 128, 0, stream>>>(
        node_start, edge_idx, hef, out);
}